// Round 1
// 989.906 us; speedup vs baseline: 1.0461x; 1.0461x over previous
//
#include <hip/hip_runtime.h>
#include <hip/hip_bf16.h>

typedef __bf16 bf16x8 __attribute__((ext_vector_type(8)));
typedef __bf16 bf16x4 __attribute__((ext_vector_type(4)));
typedef float  f32x4  __attribute__((ext_vector_type(4)));

#define MFMA16 __builtin_amdgcn_mfma_f32_16x16x32_bf16

// ---------------------------------------------------------------------------
// Weight prep: fp32 [K][Nw] row-major -> bf16 fragment layout
// [kchunk][ntile][lane][8], where lane = (k_quad<<4) | n_low4,
// frag[j] = W[kchunk*32 + quad*8 + j][ntile*16 + (lane&15)].
// Used as the *A* operand of MFMA (A and B frag layouts are identical
// functions of (lane, j)), so D = W_frag · h_frag is the transposed tile:
// lane holds node = lane&15, out-cols q*4+r  ->  wide coalesced stores.
// ---------------------------------------------------------------------------
__global__ void shuffle_weights(const float* __restrict__ W, __bf16* __restrict__ out,
                                int K, int Nw) {
    int tid = blockIdx.x * 256 + threadIdx.x;
    int NT = Nw >> 4;
    int total = (K >> 5) * NT * 64;
    if (tid >= total) return;
    int lane = tid & 63;
    int rest = tid >> 6;
    int nt = rest % NT;
    int kc = rest / NT;
    int q = lane >> 4;
    int n = nt * 16 + (lane & 15);
    const float* src = W + (size_t)(kc * 32 + q * 8) * Nw + n;
    __bf16* dst = out + (size_t)tid * 8;
#pragma unroll
    for (int j = 0; j < 8; ++j) dst[j] = (__bf16)src[(size_t)j * Nw];
}

// ---------------------------------------------------------------------------
// Phase 1: h = relu(relu(X@W1 + b1)@W2 + b2), store bf16 [N][128].
// Block = 256 threads = 4 waves; wave covers 32 rows (2 node-tiles of 16).
// MFMA operands swapped (weights as A): accumulator lane layout is
// (node = lane&15, col = q*4+r) so LDS/global writes are 8B bf16x4.
// h1 LDS handoff is same-wave only -> no __syncthreads needed.
// ---------------------------------------------------------------------------
__global__ __launch_bounds__(256) void phase1(
    const float* __restrict__ feat,
    const __bf16* __restrict__ W1s, const float* __restrict__ b1,
    const __bf16* __restrict__ W2s, const float* __restrict__ b2,
    __bf16* __restrict__ hbuf)
{
    __shared__ __bf16 h1s[128 * 136];  // row stride 136 bf16 = 272B
    const int lane = threadIdx.x & 63;
    const int wave = threadIdx.x >> 6;
    const int q    = lane >> 4;
    const int mr   = lane & 15;
    const long base = (long)blockIdx.x * 128 + wave * 32;

    const f32x4 fz = {0.f, 0.f, 0.f, 0.f};

    // ---- layer 1: [32 x 256] @ [256 x 128] ----
    f32x4 acc[8][2];   // [col-tile][node-tile]
#pragma unroll
    for (int ct = 0; ct < 8; ++ct) { acc[ct][0] = fz; acc[ct][1] = fz; }

#pragma unroll
    for (int kc = 0; kc < 8; ++kc) {
        bf16x8 af[2];
#pragma unroll
        for (int mt = 0; mt < 2; ++mt) {
            const float* p = feat + (base + mt * 16 + mr) * 256 + kc * 32 + q * 8;
            f32x4 f0 = *(const f32x4*)p;
            f32x4 f1 = *(const f32x4*)(p + 4);
#pragma unroll
            for (int j = 0; j < 4; ++j) {
                af[mt][j]     = (__bf16)f0[j];
                af[mt][4 + j] = (__bf16)f1[j];
            }
        }
#pragma unroll
        for (int ct = 0; ct < 8; ++ct) {
            bf16x8 bf = *(const bf16x8*)(W1s + (size_t)((kc * 8 + ct) * 64 + lane) * 8);
            acc[ct][0] = MFMA16(bf, af[0], acc[ct][0], 0, 0, 0);
            acc[ct][1] = MFMA16(bf, af[1], acc[ct][1], 0, 0, 0);
        }
    }

    // bias + relu -> LDS, 8B stores (lane owns node mr, cols ct*16+q*4..+3)
#pragma unroll
    for (int mt = 0; mt < 2; ++mt)
#pragma unroll
        for (int ct = 0; ct < 8; ++ct) {
            f32x4 bb = *(const f32x4*)(b1 + ct * 16 + q * 4);
            bf16x4 v;
#pragma unroll
            for (int r = 0; r < 4; ++r) {
                float x = acc[ct][mt][r] + bb[r];
                v[r] = (__bf16)(x > 0.f ? x : 0.f);
            }
            *(bf16x4*)&h1s[(wave * 32 + mt * 16 + mr) * 136 + ct * 16 + q * 4] = v;
        }
    // no barrier: producer lanes and consumer lanes are in the same wave,
    // DS pipe is in-order per wave and compiler inserts lgkmcnt waits.

    // ---- layer 2: [32 x 128] @ [128 x 128] ----
    bf16x8 af2[2][4];
#pragma unroll
    for (int mt = 0; mt < 2; ++mt)
#pragma unroll
        for (int kc = 0; kc < 4; ++kc)
            af2[mt][kc] = *(const bf16x8*)&h1s[(wave * 32 + mt * 16 + mr) * 136 + kc * 32 + q * 8];

    f32x4 acc2[8][2];
#pragma unroll
    for (int ct = 0; ct < 8; ++ct) { acc2[ct][0] = fz; acc2[ct][1] = fz; }

#pragma unroll
    for (int kc = 0; kc < 4; ++kc)
#pragma unroll
        for (int ct = 0; ct < 8; ++ct) {
            bf16x8 bf = *(const bf16x8*)(W2s + (size_t)((kc * 8 + ct) * 64 + lane) * 8);
            acc2[ct][0] = MFMA16(bf, af2[0][kc], acc2[ct][0], 0, 0, 0);
            acc2[ct][1] = MFMA16(bf, af2[1][kc], acc2[ct][1], 0, 0, 0);
        }

    // bias + relu -> hbuf bf16 [N][128], 8B stores
#pragma unroll
    for (int mt = 0; mt < 2; ++mt)
#pragma unroll
        for (int ct = 0; ct < 8; ++ct) {
            f32x4 bb = *(const f32x4*)(b2 + ct * 16 + q * 4);
            bf16x4 v;
#pragma unroll
            for (int r = 0; r < 4; ++r) {
                float x = acc2[ct][mt][r] + bb[r];
                v[r] = (__bf16)(x > 0.f ? x : 0.f);
            }
            *(bf16x4*)&hbuf[(base + mt * 16 + mr) * 128 + ct * 16 + q * 4] = v;
        }
}

// ---------------------------------------------------------------------------
// Phase 2: edge = [h[parent] | h] @ We + be  (K=256, Nw=256),
//          unary = h @ Wu + bu               (K=128, Nw=16).
// Swapped-operand MFMA: every acc f32x4 is one aligned float4 store
// (34 dwordx4 stores/thread vs 136 scalar dwords before).
// A-frags gathered per-kc inside the loop: live set ~100 VGPR, no spill,
// loads interleave with MFMAs. Out row = [unary(16) | edge(256)] fp32 x272.
// ---------------------------------------------------------------------------
__global__ __launch_bounds__(256) void phase2(
    const __bf16* __restrict__ hbuf, const int* __restrict__ parent,
    const __bf16* __restrict__ WeS, const float* __restrict__ be,
    const __bf16* __restrict__ WuS, const float* __restrict__ bu,
    float* __restrict__ out)
{
    const int lane = threadIdx.x & 63;
    const int q    = lane >> 4;
    const int mr   = lane & 15;
    const long base = (long)blockIdx.x * 128 + (threadIdx.x >> 6) * 32;

    const f32x4 fz = {0.f, 0.f, 0.f, 0.f};

    const long n0 = base + mr;
    const long n1 = base + 16 + mr;
    const __bf16* hn0 = hbuf + n0 * 128;
    const __bf16* hn1 = hbuf + n1 * 128;
    const __bf16* hp0 = hbuf + (long)parent[n0] * 128;
    const __bf16* hp1 = hbuf + (long)parent[n1] * 128;

    // ---- unary: h @ Wu (child half) ----
    {
        f32x4 au0 = fz, au1 = fz;
#pragma unroll
        for (int kc = 0; kc < 4; ++kc) {
            bf16x8 a0 = *(const bf16x8*)(hn0 + kc * 32 + q * 8);
            bf16x8 a1 = *(const bf16x8*)(hn1 + kc * 32 + q * 8);
            bf16x8 bf = *(const bf16x8*)(WuS + (size_t)(kc * 64 + lane) * 8);
            au0 = MFMA16(bf, a0, au0, 0, 0, 0);
            au1 = MFMA16(bf, a1, au1, 0, 0, 0);
        }
        f32x4 bb = *(const f32x4*)(bu + q * 4);
        *(f32x4*)&out[n0 * 272 + q * 4] = au0 + bb;
        *(f32x4*)&out[n1 * 272 + q * 4] = au1 + bb;
    }

    // ---- edge: two N-halves of 128 cols each ----
#pragma unroll 1
    for (int nh = 0; nh < 2; ++nh) {
        f32x4 acc[8][2];   // [col-tile][node-tile]
#pragma unroll
        for (int nt = 0; nt < 8; ++nt) { acc[nt][0] = fz; acc[nt][1] = fz; }

#pragma unroll
        for (int kc = 0; kc < 8; ++kc) {
            const __bf16* s0 = (kc < 4) ? (hp0 + kc * 32) : (hn0 + (kc - 4) * 32);
            const __bf16* s1 = (kc < 4) ? (hp1 + kc * 32) : (hn1 + (kc - 4) * 32);
            bf16x8 a0 = *(const bf16x8*)(s0 + q * 8);
            bf16x8 a1 = *(const bf16x8*)(s1 + q * 8);
#pragma unroll
            for (int nt = 0; nt < 8; ++nt) {
                bf16x8 bf = *(const bf16x8*)(WeS + (size_t)((kc * 16 + nh * 8 + nt) * 64 + lane) * 8);
                acc[nt][0] = MFMA16(bf, a0, acc[nt][0], 0, 0, 0);
                acc[nt][1] = MFMA16(bf, a1, acc[nt][1], 0, 0, 0);
            }
        }

#pragma unroll
        for (int nt = 0; nt < 8; ++nt) {
            int c0 = nh * 128 + nt * 16 + q * 4;
            f32x4 bb = *(const f32x4*)(be + c0);
            *(f32x4*)&out[n0 * 272 + 16 + c0] = acc[nt][0] + bb;
            *(f32x4*)&out[n1 * 272 + 16 + c0] = acc[nt][1] + bb;
        }
    }
}

// ---------------------------------------------------------------------------
// ws layout (bytes):
//   0        W1s   (256x128 bf16 shuffled)  65536
//   65536    W2s   (128x128)                32768
//   98304    WuS   (128x16)                  4096
//   102400   WeS   (256x256)               131072
//   233472   hbuf  (400000x128 bf16)   102400000
// total ~97.9 MB
// ---------------------------------------------------------------------------
extern "C" void kernel_launch(void* const* d_in, const int* in_sizes, int n_in,
                              void* d_out, int out_size, void* d_ws, size_t ws_size,
                              hipStream_t stream) {
    const float* feat  = (const float*)d_in[0];
    const int*   parent = (const int*)d_in[1];
    const float* W1 = (const float*)d_in[2];
    const float* b1 = (const float*)d_in[3];
    const float* W2 = (const float*)d_in[4];
    const float* b2 = (const float*)d_in[5];
    const float* Wu = (const float*)d_in[6];
    const float* bu = (const float*)d_in[7];
    const float* We = (const float*)d_in[8];
    const float* be = (const float*)d_in[9];
    float* out = (float*)d_out;

    char* ws = (char*)d_ws;
    __bf16* W1s  = (__bf16*)(ws);
    __bf16* W2s  = (__bf16*)(ws + 65536);
    __bf16* WuS  = (__bf16*)(ws + 98304);
    __bf16* WeS  = (__bf16*)(ws + 102400);
    __bf16* hbuf = (__bf16*)(ws + 233472);

    shuffle_weights<<<16, 256, 0, stream>>>(W1, W1s, 256, 128);
    shuffle_weights<<<8,  256, 0, stream>>>(W2, W2s, 128, 128);
    shuffle_weights<<<1,  256, 0, stream>>>(Wu, WuS, 128, 16);
    shuffle_weights<<<32, 256, 0, stream>>>(We, WeS, 256, 256);

    const int nblocks = 400000 / 128;  // 3125
    phase1<<<nblocks, 256, 0, stream>>>(feat, W1s, b1, W2s, b2, hbuf);
    phase2<<<nblocks, 256, 0, stream>>>(hbuf, parent, WeS, be, WuS, bu, out);
}